// Round 11
// baseline (860.649 us; speedup 1.0000x reference)
//
#include <hip/hip_runtime.h>

// ---------------------------------------------------------------------------
// GRU (T=256, B=1024, IN=128, H=256) + per-step BatchNorm, MI355X.
// R16->R17: yfused occupancy doubled (512 -> 1024 thr, 16 waves = 4/SIMD).
// Same medicine as R15's gru win: yfused was ~100us vs its 43us HBM floor,
// latency-bound at 8 waves/CU. Wave now owns 64 rows (4 s-iters), ypk = 16
// uintx4 (64 AGPRs), LDS 81KB. gru (R15/R16, 676us) and pack_all untouched.
// Resource-box notes: gru register pool exactly full at 4 waves/SIMD x
// (64V+64A); LDS 151.5/160 KB; grid capped at 64 by B/16. gru is CLOSED.
// ---------------------------------------------------------------------------

typedef _Float16 half8 __attribute__((ext_vector_type(8)));
typedef float floatx4 __attribute__((ext_vector_type(4)));
typedef unsigned uintx4 __attribute__((ext_vector_type(4)));

#define EPS_BN 1e-5f

// ws layout (bytes):
//   [0,       524288)   wc: folded gate weights, 16 cgs x 32 tiles x 1 KB
//   [524288, 1114112)   w0: step-0 weights, 16 cgs x 36 tiles x 1 KB
//   [1114112,1179648)   wl: W_lin B-frags, 64 tiles x 1 KB
//   [1179648,1183744)   bias0: 256 x float4
//   [1183744,1187840)   bc: 256 x float4 folded biases
#define WS_WC 0
#define WS_W0 524288
#define WS_WL 1114112
#define WS_B0 1179648
#define WS_BC 1183744

static __device__ __forceinline__ unsigned short f2h(float f) {
    union { _Float16 h; unsigned short u; } v;
    v.h = (_Float16)f;                      // v_cvt_f16_f32, RNE
    return v.u;
}
static __device__ __forceinline__ unsigned pack2h(float a, float b) {
    return (unsigned)f2h(a) | ((unsigned)f2h(b) << 16);
}
static __device__ __forceinline__ float2 up2(unsigned u) {
    union { unsigned v; _Float16 h[2]; } x; x.v = u;
    return make_float2((float)x.h[0], (float)x.h[1]);
}
static __device__ __forceinline__ half8 as_h8(uint4 v) {
    union { uint4 u; half8 h; } x; x.u = v; return x.h;
}
// Load a 16B weight fragment and force it into AGPRs (opaque, non-remat).
static __device__ __forceinline__ half8 ld_agpr(const uint4* p) {
    uintx4 v = *(const uintx4*)p;
    asm volatile("; wpin" : "+a"(v));
    union { uintx4 u; half8 h; } x; x.u = v; return x.h;
}
// Fast activations: v_rcp_f32 + v_exp_f32 (1 ulp each).
static __device__ __forceinline__ float sigm(float x) {
    return __builtin_amdgcn_rcpf(1.0f + __builtin_amdgcn_exp2f(-1.442695041f * x));
}
static __device__ __forceinline__ float tanh_fast(float x) {
    return 1.0f - 2.0f * __builtin_amdgcn_rcpf(1.0f + __builtin_amdgcn_exp2f(2.885390082f * x));
}
// Workgroup barrier that drains LDS only (no vmcnt(0) store-drain).
static __device__ __forceinline__ void bar_lgkm() {
    asm volatile("s_waitcnt lgkmcnt(0)\n\ts_barrier" ::: "memory");
}
#define MFMA16(A, B, C) __builtin_amdgcn_mfma_f32_16x16x32_f16((A), (B), (C), 0, 0, 0)

// ---------------------------------------------------------------------------
// pack_all: [blocks 0..160] original weights -> w0 tiles + wl + bias0;
// [blocks 161..672] one wc tile each (4-way ii-split fold, LDS combine);
// [block 673] folded biases bc.
// B-frag 16x16x32: lane l holds B[n0+(l&15)][k0+(l>>4)*8+j]. (R16-verified)
// ---------------------------------------------------------------------------
__global__ void pack_all_kernel(const float* __restrict__ W_ih, const float* __restrict__ W_hh,
                                const float* __restrict__ W_lin, const float* __restrict__ b_ih,
                                const float* __restrict__ b_hh, const float* __restrict__ b_lin,
                                uint4* __restrict__ w0, uint4* __restrict__ wl,
                                float4* __restrict__ bias0,
                                uint4* __restrict__ wc, float4* __restrict__ bc)
{
    __shared__ float sh[256][8];
    if (blockIdx.x < 161) {
        int i = blockIdx.x * 256 + threadIdx.x;
        if (i < 36864) {                       // 576 w0 tiles x 64 lanes
            int lane = i & 63, tile = i >> 6;
            int w = tile / 36, rem = tile - w * 36;
            int g = rem / 12, kt = rem - g * 12;
            int n = g * 256 + (w << 4) + (lane & 15);
            int k0 = (kt << 5) + ((lane >> 4) << 3);
            const float* p = (k0 < 128) ? (W_ih + n * 128 + k0)
                                        : (W_hh + n * 256 + (k0 - 128));
            unsigned short h[8];
            #pragma unroll
            for (int j = 0; j < 8; ++j) h[j] = f2h(p[j]);
            uint4 v;
            v.x = (unsigned)h[0] | ((unsigned)h[1] << 16);
            v.y = (unsigned)h[2] | ((unsigned)h[3] << 16);
            v.z = (unsigned)h[4] | ((unsigned)h[5] << 16);
            v.w = (unsigned)h[6] | ((unsigned)h[7] << 16);
            w0[i] = v;
        } else if (i < 40960) {                // 64 wl tiles x 64 lanes
            int i2 = i - 36864;
            int lane = i2 & 63, tile = i2 >> 6;        // tile = nt*8 + kt
            int n = (tile >> 3) * 16 + (lane & 15);
            int k0 = ((tile & 7) << 5) + ((lane >> 4) << 3);
            const float* p = W_lin + n * 256 + k0;
            unsigned short h[8];
            #pragma unroll
            for (int j = 0; j < 8; ++j) h[j] = f2h(p[j]);
            uint4 v;
            v.x = (unsigned)h[0] | ((unsigned)h[1] << 16);
            v.y = (unsigned)h[2] | ((unsigned)h[3] << 16);
            v.z = (unsigned)h[4] | ((unsigned)h[5] << 16);
            v.w = (unsigned)h[6] | ((unsigned)h[7] << 16);
            wl[i2] = v;
        } else if (i < 41216) {
            int cb = i - 40960;
            bias0[cb] = make_float4(b_ih[cb] + b_hh[cb],
                                    b_ih[256 + cb] + b_hh[256 + cb],
                                    b_ih[512 + cb], b_hh[512 + cb]);
        }
        return;
    }
    int fb = blockIdx.x - 161;
    if (fb < 512) {                        // one wc tile per block, 4-way split
        const int tid  = threadIdx.x;
        const int q    = tid >> 6;         // ii quarter 0..3
        const int lane = tid & 63;
        const int tile = fb;
        int w = tile >> 5, r = tile & 31;
        int g = r >> 3, kt = r & 7;
        int c = (w << 4) + (lane & 15);
        int k0 = (kt << 5) + ((lane >> 4) << 3);
        float s[8];
        #pragma unroll
        for (int j = 0; j < 8; ++j) s[j] = 0.0f;
        if (g == 3) {
            if (q == 0) {
                #pragma unroll
                for (int j = 0; j < 8; ++j) s[j] = W_hh[(512 + c) * 256 + k0 + j];
            }
        } else {
            int row = g * 256 + c;
            const float* wi = W_ih + row * 128 + (q << 5);
            for (int ii = 0; ii < 32; ++ii) {
                float wv = wi[ii];
                const float* wrow = W_lin + ((q << 5) + ii) * 256 + k0;
                #pragma unroll
                for (int j = 0; j < 8; ++j) s[j] += wv * wrow[j];
            }
            if (g < 2 && q == 0) {
                #pragma unroll
                for (int j = 0; j < 8; ++j) s[j] += W_hh[row * 256 + k0 + j];
            }
        }
        #pragma unroll
        for (int j = 0; j < 8; ++j) sh[tid][j] = s[j];
        __syncthreads();
        if (q == 0) {
            #pragma unroll
            for (int j = 0; j < 8; ++j)
                s[j] += sh[tid + 64][j] + sh[tid + 128][j] + sh[tid + 192][j];
            unsigned short h[8];
            #pragma unroll
            for (int j = 0; j < 8; ++j) h[j] = f2h(s[j]);
            uint4 v;
            v.x = (unsigned)h[0] | ((unsigned)h[1] << 16);
            v.y = (unsigned)h[2] | ((unsigned)h[3] << 16);
            v.z = (unsigned)h[4] | ((unsigned)h[5] << 16);
            v.w = (unsigned)h[6] | ((unsigned)h[7] << 16);
            wc[tile * 64 + lane] = v;
        }
    } else {                               // fb == 512: folded biases
        int c = threadIdx.x;
        float d0 = 0.f, d1 = 0.f, d2 = 0.f;
        for (int ii = 0; ii < 128; ++ii) {
            float bl = b_lin[ii];
            d0 += bl * W_ih[c * 128 + ii];
            d1 += bl * W_ih[(256 + c) * 128 + ii];
            d2 += bl * W_ih[(512 + c) * 128 + ii];
        }
        bc[c] = make_float4(b_ih[c] + b_hh[c] + d0,
                            b_ih[256 + c] + b_hh[256 + c] + d1,
                            b_ih[512 + c] + d2,
                            b_hh[512 + c]);
    }
}

// ---------------------------------------------------------------------------
// Recurrence: 64 blocks x 1024 thr (16 waves, 4/SIMD). Block owns 16 batch
// rows; wave w (0..15) owns ONE col-group: cols c0 = w*16 .. w*16+15.
// Residency per wave (exactly fills the register pool at 4 waves/SIMD):
//   AGPR 16 tiles (64 AGPRs, "+a" pinned): r kt0-7, z kt0-7
//   LDS   8 tiles: in kt0-3 [slots 0-3], hn kt0-3 [slots 4-7]
//   streamed 8/step: in kt4-7 (tiles 20-23), hn kt4-7 (tiles 28-31),
//       all issued at loop top (32-VGPR peak)
// LDS (uint4): [0,1024) h-frag dbuf | [1024,1280) xbuf | [1280,9472)
// per-wave weight tiles (8/wave). One lgkm barrier/step. (R15/R16-verified)
// ---------------------------------------------------------------------------
__global__ __launch_bounds__(1024, 4) void gru_kernel(
    const float* __restrict__ inputs,
    const float* __restrict__ hidden,
    const uint4* __restrict__ wc,
    const uint4* __restrict__ w0,
    const float4* __restrict__ bias0,
    const float4* __restrict__ bcp,
    float* __restrict__ out)
{
    __shared__ uint4 lds[9472];            // 151552 B

    const int tid  = threadIdx.x;
    const int lane = tid & 63;
    const int w    = tid >> 6;             // wave 0..15
    const int quad = lane >> 4;
    const int nc   = lane & 15;
    const int r0   = blockIdx.x << 4;
    const int c0   = (w << 4) + nc;
    const float4 bc0 = bcp[c0];
    const uint4* wcw = wc + (size_t)w * 2048;         // 32 tiles * 64

    // ---- AGPR-pinned tiles: r kt0-7, z kt0-7 for this col-group
    half8 wr[8], wz[8];
    #pragma unroll
    for (int kt = 0; kt < 8; ++kt) {
        wr[kt] = ld_agpr(&wcw[kt * 64 + lane]);
        wz[kt] = ld_agpr(&wcw[(8 + kt) * 64 + lane]);
    }

    // ---- LDS-resident tiles: in kt0-3 (tiles 16-19), hn kt0-3 (tiles 24-27)
    const int wbase = 1280 + (w << 9);     // 512 uint4 per wave
    #pragma unroll
    for (int i = 0; i < 4; ++i) {
        lds[wbase + (i << 6) + lane]       = wcw[(16 + i) * 64 + lane];
        lds[wbase + ((4 + i) << 6) + lane] = wcw[(24 + i) * 64 + lane];
    }

    // fp32 master hidden state: rows quad*4+d, col c0
    float hreg[4];
    #pragma unroll
    for (int d = 0; d < 4; ++d)
        hreg[d] = hidden[(r0 + (quad << 2) + d) * 256 + c0];

    // A-frag write addressing: col c0 -> kt = w>>1, kp = (w&1)*16+nc;
    // frag lane lf = (kp>>3)*16 + quad*4; u16 idx = ((kt*64+lf)<<3)+(kp&7)
    unsigned short* lds_u16 = (unsigned short*)lds;
    const int kp  = ((w & 1) << 4) + nc;
    const int lf  = ((kp >> 3) << 4) + (quad << 2);
    const int hfb0 = (((w >> 1) * 64 + lf) << 3) + (kp & 7);

    // init h(0) frags -> buf0
    for (int idx = tid; idx < 2048; idx += 1024) {
        int ktl = idx >> 8;
        int rem = idx & 255;
        int lfr = rem >> 2, jg = rem & 3;
        int m = lfr & 15;
        int hc = ktl * 32 + (lfr >> 4) * 8 + jg * 2;
        const float* p = hidden + (r0 + m) * 256 + hc;
        unsigned pk = (unsigned)f2h(p[0]) | ((unsigned)f2h(p[1]) << 16);
        ((unsigned*)lds)[(ktl * 64 + lfr) * 4 + jg] = pk;
    }
    // init x frags -> xbuf
    {
        int idx = tid;
        int kt = idx >> 8, lfr = (idx >> 2) & 63, jg = idx & 3;
        int m = lfr & 15;
        int k0 = (kt << 5) + ((lfr >> 4) << 3) + (jg << 1);
        const float* p = inputs + (r0 + m) * 128 + k0;
        unsigned pk = (unsigned)f2h(p[0]) | ((unsigned)f2h(p[1]) << 16);
        ((unsigned*)lds)[(1024 + (kt << 6) + lfr) * 4 + jg] = pk;
    }
    __syncthreads();

    unsigned short* Hout = (unsigned short*)out;

    // ---- t = 0: K=384 on [x|h] with original w0 (streamed once)
    {
        const uint4* ww = w0 + (size_t)w * 2304;       // 36 tiles * 64
        floatx4 ar = {0.f,0.f,0.f,0.f}, az = {0.f,0.f,0.f,0.f};
        floatx4 ain = {0.f,0.f,0.f,0.f}, ahn = {0.f,0.f,0.f,0.f};
        #pragma unroll
        for (int kt = 0; kt < 12; ++kt) {
            half8 A = as_h8(kt < 4 ? lds[1024 + (kt << 6) + lane]
                                   : lds[((kt - 4) << 6) + lane]);
            ar = MFMA16(A, as_h8(ww[kt * 64 + lane]), ar);
            az = MFMA16(A, as_h8(ww[(12 + kt) * 64 + lane]), az);
            if (kt < 4)
                ain = MFMA16(A, as_h8(ww[(24 + kt) * 64 + lane]), ain);
            else
                ahn = MFMA16(A, as_h8(ww[(24 + kt) * 64 + lane]), ahn);
        }
        float4 b0 = bias0[c0];
        #pragma unroll
        for (int d = 0; d < 4; ++d) {
            float rr = sigm(ar[d] + b0.x);
            float zz = sigm(az[d] + b0.y);
            float nn = tanh_fast(ain[d] + b0.z + rr * (ahn[d] + b0.w));
            float hnew = (1.0f - zz) * nn + zz * hreg[d];
            hreg[d] = hnew;
            unsigned short hu = f2h(hnew);
            lds_u16[4096 + hfb0 + (d << 3)] = hu;      // buf1
            Hout[((size_t)(r0 + (quad << 2) + d) << 8) + c0] = hu;
        }
        bar_lgkm();
    }

    for (int t = 1; t < 256; ++t) {
        const int rb   = (t & 1) << 9;                 // read buf (uint4)
        const int wb16 = (((t + 1) & 1) << 9) << 3;    // write buf (u16)

        // opaque per-iteration pointer: streamed tiles cannot be hoisted
        const uint4* sp = wcw + lane;
        asm("" : "+v"(sp));

        // streamed tiles: in kt4-7 (tiles 20-23), hn kt4-7 (tiles 28-31).
        uint4 si[4], sh[4];
        si[0] = sp[20 * 64]; si[1] = sp[21 * 64];
        si[2] = sp[22 * 64]; si[3] = sp[23 * 64];
        sh[0] = sp[28 * 64]; sh[1] = sp[29 * 64];
        sh[2] = sp[30 * 64]; sh[3] = sp[31 * 64];

        floatx4 ar = {0.f,0.f,0.f,0.f}, az = {0.f,0.f,0.f,0.f};
        floatx4 ai = {0.f,0.f,0.f,0.f}, ah = {0.f,0.f,0.f,0.f};

        #pragma unroll
        for (int kt = 0; kt < 8; ++kt) {
            half8 A = as_h8(lds[rb + (kt << 6) + lane]);
            ar = MFMA16(A, wr[kt], ar);
            az = MFMA16(A, wz[kt], az);
            half8 Bi = (kt < 4) ? as_h8(lds[wbase + (kt << 6) + lane])
                                : as_h8(si[kt - 4]);
            ai = MFMA16(A, Bi, ai);
            half8 Bh = (kt < 4) ? as_h8(lds[wbase + ((4 + kt) << 6) + lane])
                                : as_h8(sh[kt - 4]);
            ah = MFMA16(A, Bh, ah);
        }

        const size_t obase = (size_t)t * 1024 + r0 + (quad << 2);
        #pragma unroll
        for (int d = 0; d < 4; ++d) {
            float rr = sigm(ar[d] + bc0.x);
            float zz = sigm(az[d] + bc0.y);
            float nn = tanh_fast(ai[d] + bc0.z + rr * (ah[d] + bc0.w));
            float hnew = (1.0f - zz) * nn + zz * hreg[d];
            hreg[d] = hnew;
            unsigned short hu = f2h(hnew);
            lds_u16[wb16 + hfb0 + (d << 3)] = hu;
            Hout[((obase + d) << 8) + c0] = hu;
        }
        bar_lgkm();
    }
}

// ---------------------------------------------------------------------------
// yfused: one block per timestep t (grid 256, 1/CU), R17: 1024 thr = 16
// waves (4/SIMD, was 8 waves). Wave w computes y rows [w*64, w*64+64) x all
// 128 cols: A-frags straight from H global (u16), B from 64KB LDS, y packed
// fp16 -> 16 uintx4/thread pinned in AGPRs (64 AGPRs); s1/s2 fp32 per lane.
// Then shfl + 16-wave LDS reduce -> mean/scale; unpack, normalize, write
// fp32 out. In-place over d_out (H reads all precede the stats barrier).
// LDS 81 KB.
// ---------------------------------------------------------------------------
__global__ __launch_bounds__(1024, 4) void yfused_kernel(
    const uint4* __restrict__ wl, const float* __restrict__ b_lin,
    float* __restrict__ out)
{
    __shared__ uint4 bfr[4096];            // 64 KB: 64 W_lin tiles
    __shared__ float sred[16][256];        // 16 KB: per-wave s1[128] | s2[128]
    __shared__ float snorm[256];           // mean[128] | scale[128]

    const int tid  = threadIdx.x;
    const int lane = tid & 63;
    const int w    = tid >> 6;             // wave 0..15
    const int quad = lane >> 4;
    const int nc   = lane & 15;
    const int t    = blockIdx.x;

    const unsigned short* H = (const unsigned short*)out + (size_t)t * 262144;
    float* Y = out + (size_t)t * 131072;

    // stage all W_lin B-frags (4096 uint4 / 1024 thr)
    #pragma unroll
    for (int i = 0; i < 4; ++i)
        bfr[(i << 10) + tid] = wl[(i << 10) + tid];

    float blv[8];
    #pragma unroll
    for (int c = 0; c < 8; ++c) blv[c] = b_lin[(c << 4) + nc];

    __syncthreads();

    const int rw0 = w << 6;                // wave's first row of 64
    float s1[8], s2[8];
    #pragma unroll
    for (int c = 0; c < 8; ++c) { s1[c] = 0.f; s2[c] = 0.f; }
    uintx4 ypk[16];

    #pragma unroll
    for (int s = 0; s < 4; ++s) {
        const unsigned short* hrow = H + (size_t)(rw0 + (s << 4) + nc) * 256 + (quad << 3);
        uint4 A[8];
        #pragma unroll
        for (int kt = 0; kt < 8; ++kt)
            A[kt] = *(const uint4*)(hrow + (kt << 5));
        unsigned te0 = 0, te1 = 0;
        #pragma unroll
        for (int c = 0; c < 8; ++c) {
            floatx4 acc = {0.f, 0.f, 0.f, 0.f};
            #pragma unroll
            for (int kt = 0; kt < 8; ++kt)
                acc = MFMA16(as_h8(A[kt]), as_h8(bfr[(((c << 3) + kt) << 6) + lane]), acc);
            float y0 = acc[0] + blv[c], y1 = acc[1] + blv[c];
            float y2 = acc[2] + blv[c], y3 = acc[3] + blv[c];
            s1[c] += (y0 + y1) + (y2 + y3);
            s2[c] += (y0 * y0 + y1 * y1) + (y2 * y2 + y3 * y3);
            unsigned q0 = pack2h(y0, y1), q1 = pack2h(y2, y3);
            if ((c & 1) == 0) { te0 = q0; te1 = q1; }
            else {
                uintx4 v; v[0] = te0; v[1] = te1; v[2] = q0; v[3] = q1;
                asm volatile("; ypin" : "+a"(v));
                ypk[(s << 2) + (c >> 1)] = v;
            }
        }
    }

    // cross-quad then cross-wave stats reduce
    #pragma unroll
    for (int c = 0; c < 8; ++c) {
        s1[c] += __shfl_xor(s1[c], 16); s1[c] += __shfl_xor(s1[c], 32);
        s2[c] += __shfl_xor(s2[c], 16); s2[c] += __shfl_xor(s2[c], 32);
    }
    if (lane < 16) {
        #pragma unroll
        for (int c = 0; c < 8; ++c) {
            sred[w][(c << 4) + lane]       = s1[c];
            sred[w][128 + (c << 4) + lane] = s2[c];
        }
    }
    __syncthreads();
    if (tid < 128) {
        float a1 = 0.f, a2 = 0.f;
        #pragma unroll
        for (int w2 = 0; w2 < 16; ++w2) {
            a1 += sred[w2][tid];
            a2 += sred[w2][128 + tid];
        }
        float mean = a1 * (1.0f / 1024.0f);
        float var  = a2 * (1.0f / 1024.0f) - mean * mean;
        snorm[tid]       = mean;
        snorm[128 + tid] = rsqrtf(var + EPS_BN);
    }
    __syncthreads();

    float mn[8], scl[8];
    #pragma unroll
    for (int c = 0; c < 8; ++c) {
        mn[c]  = snorm[(c << 4) + nc];
        scl[c] = snorm[128 + (c << 4) + nc];
    }

    #pragma unroll
    for (int s = 0; s < 4; ++s) {
        float* yrow = Y + (size_t)(rw0 + (s << 4) + (quad << 2)) * 128 + nc;
        #pragma unroll
        for (int cp = 0; cp < 4; ++cp) {
            uintx4 v = ypk[(s << 2) + cp];
            const int c0 = cp << 1, c1 = c0 + 1;
            float2 a01 = up2(v[0]), a23 = up2(v[1]);   // col-tile c0, d0..3
            float2 b01 = up2(v[2]), b23 = up2(v[3]);   // col-tile c1, d0..3
            const int o0 = cp << 5, o1 = o0 + 16;
            yrow[0 * 128 + o0] = (a01.x - mn[c0]) * scl[c0];
            yrow[1 * 128 + o0] = (a01.y - mn[c0]) * scl[c0];
            yrow[2 * 128 + o0] = (a23.x - mn[c0]) * scl[c0];
            yrow[3 * 128 + o0] = (a23.y - mn[c0]) * scl[c0];
            yrow[0 * 128 + o1] = (b01.x - mn[c1]) * scl[c1];
            yrow[1 * 128 + o1] = (b01.y - mn[c1]) * scl[c1];
            yrow[2 * 128 + o1] = (b23.x - mn[c1]) * scl[c1];
            yrow[3 * 128 + o1] = (b23.y - mn[c1]) * scl[c1];
        }
    }
}

extern "C" void kernel_launch(void* const* d_in, const int* in_sizes, int n_in,
                              void* d_out, int out_size, void* d_ws, size_t ws_size,
                              hipStream_t stream) {
    (void)in_sizes; (void)n_in; (void)out_size; (void)ws_size;
    const float* inputs = (const float*)d_in[0];
    const float* hidden = (const float*)d_in[1];
    const float* W_ih   = (const float*)d_in[2];
    const float* b_ih   = (const float*)d_in[3];
    const float* W_hh   = (const float*)d_in[4];
    const float* b_hh   = (const float*)d_in[5];
    const float* W_lin  = (const float*)d_in[6];
    const float* b_lin  = (const float*)d_in[7];

    char* ws = (char*)d_ws;
    uint4*  wcp   = (uint4*)(ws + WS_WC);
    uint4*  w0p   = (uint4*)(ws + WS_W0);
    uint4*  wlp   = (uint4*)(ws + WS_WL);
    float4* bias0 = (float4*)(ws + WS_B0);
    float4* bcp   = (float4*)(ws + WS_BC);

    pack_all_kernel<<<674, 256, 0, stream>>>(W_ih, W_hh, W_lin, b_ih, b_hh, b_lin,
                                             w0p, wlp, bias0, wcp, bcp);
    gru_kernel<<<64, 1024, 0, stream>>>(inputs, hidden, wcp, w0p, bias0, bcp, (float*)d_out);
    yfused_kernel<<<256, 1024, 0, stream>>>(wlp, b_lin, (float*)d_out);
}

// Round 12
// 852.807 us; speedup vs baseline: 1.0092x; 1.0092x over previous
//
#include <hip/hip_runtime.h>

// ---------------------------------------------------------------------------
// GRU (T=256, B=1024, IN=128, H=256) + per-step BatchNorm, MI355X.
// R17->R18: FINAL CONFIG — revert yfused to R16's 512-thr version (R17's
// 16-wave yfused was neutral-to-negative: yfused is L3-BW-bound, not
// latency-bound). This is the best-measured assembly (854.4us):
//   gru:    R15/R16 (64 blk x 1024 thr, 16 waves, 4/SIMD; 676us). Register
//           pool exactly full at every viable occupancy; grid capped at 64
//           by MFMA M=16; LDS 151.5/160KB. CLOSED.
//   yfused: R11/R16 (256 blk x 512 thr; y in AGPRs; stats+norm fused).
//   pack:   R16 (4-way parallel fold).
// Session: 1063.8 -> 854.4us (-19.6%).
// ---------------------------------------------------------------------------

typedef _Float16 half8 __attribute__((ext_vector_type(8)));
typedef float floatx4 __attribute__((ext_vector_type(4)));
typedef unsigned uintx4 __attribute__((ext_vector_type(4)));

#define EPS_BN 1e-5f

// ws layout (bytes):
//   [0,       524288)   wc: folded gate weights, 16 cgs x 32 tiles x 1 KB
//   [524288, 1114112)   w0: step-0 weights, 16 cgs x 36 tiles x 1 KB
//   [1114112,1179648)   wl: W_lin B-frags, 64 tiles x 1 KB
//   [1179648,1183744)   bias0: 256 x float4
//   [1183744,1187840)   bc: 256 x float4 folded biases
#define WS_WC 0
#define WS_W0 524288
#define WS_WL 1114112
#define WS_B0 1179648
#define WS_BC 1183744

static __device__ __forceinline__ unsigned short f2h(float f) {
    union { _Float16 h; unsigned short u; } v;
    v.h = (_Float16)f;                      // v_cvt_f16_f32, RNE
    return v.u;
}
static __device__ __forceinline__ unsigned pack2h(float a, float b) {
    return (unsigned)f2h(a) | ((unsigned)f2h(b) << 16);
}
static __device__ __forceinline__ float2 up2(unsigned u) {
    union { unsigned v; _Float16 h[2]; } x; x.v = u;
    return make_float2((float)x.h[0], (float)x.h[1]);
}
static __device__ __forceinline__ half8 as_h8(uint4 v) {
    union { uint4 u; half8 h; } x; x.u = v; return x.h;
}
// Load a 16B weight fragment and force it into AGPRs (opaque, non-remat).
static __device__ __forceinline__ half8 ld_agpr(const uint4* p) {
    uintx4 v = *(const uintx4*)p;
    asm volatile("; wpin" : "+a"(v));
    union { uintx4 u; half8 h; } x; x.u = v; return x.h;
}
// Fast activations: v_rcp_f32 + v_exp_f32 (1 ulp each).
static __device__ __forceinline__ float sigm(float x) {
    return __builtin_amdgcn_rcpf(1.0f + __builtin_amdgcn_exp2f(-1.442695041f * x));
}
static __device__ __forceinline__ float tanh_fast(float x) {
    return 1.0f - 2.0f * __builtin_amdgcn_rcpf(1.0f + __builtin_amdgcn_exp2f(2.885390082f * x));
}
// Workgroup barrier that drains LDS only (no vmcnt(0) store-drain).
static __device__ __forceinline__ void bar_lgkm() {
    asm volatile("s_waitcnt lgkmcnt(0)\n\ts_barrier" ::: "memory");
}
#define MFMA16(A, B, C) __builtin_amdgcn_mfma_f32_16x16x32_f16((A), (B), (C), 0, 0, 0)

// ---------------------------------------------------------------------------
// pack_all: [blocks 0..160] original weights -> w0 tiles + wl + bias0;
// [blocks 161..672] one wc tile each (4-way ii-split fold, LDS combine);
// [block 673] folded biases bc.
// B-frag 16x16x32: lane l holds B[n0+(l&15)][k0+(l>>4)*8+j]. (R16-verified)
// ---------------------------------------------------------------------------
__global__ void pack_all_kernel(const float* __restrict__ W_ih, const float* __restrict__ W_hh,
                                const float* __restrict__ W_lin, const float* __restrict__ b_ih,
                                const float* __restrict__ b_hh, const float* __restrict__ b_lin,
                                uint4* __restrict__ w0, uint4* __restrict__ wl,
                                float4* __restrict__ bias0,
                                uint4* __restrict__ wc, float4* __restrict__ bc)
{
    __shared__ float sh[256][8];
    if (blockIdx.x < 161) {
        int i = blockIdx.x * 256 + threadIdx.x;
        if (i < 36864) {                       // 576 w0 tiles x 64 lanes
            int lane = i & 63, tile = i >> 6;
            int w = tile / 36, rem = tile - w * 36;
            int g = rem / 12, kt = rem - g * 12;
            int n = g * 256 + (w << 4) + (lane & 15);
            int k0 = (kt << 5) + ((lane >> 4) << 3);
            const float* p = (k0 < 128) ? (W_ih + n * 128 + k0)
                                        : (W_hh + n * 256 + (k0 - 128));
            unsigned short h[8];
            #pragma unroll
            for (int j = 0; j < 8; ++j) h[j] = f2h(p[j]);
            uint4 v;
            v.x = (unsigned)h[0] | ((unsigned)h[1] << 16);
            v.y = (unsigned)h[2] | ((unsigned)h[3] << 16);
            v.z = (unsigned)h[4] | ((unsigned)h[5] << 16);
            v.w = (unsigned)h[6] | ((unsigned)h[7] << 16);
            w0[i] = v;
        } else if (i < 40960) {                // 64 wl tiles x 64 lanes
            int i2 = i - 36864;
            int lane = i2 & 63, tile = i2 >> 6;        // tile = nt*8 + kt
            int n = (tile >> 3) * 16 + (lane & 15);
            int k0 = ((tile & 7) << 5) + ((lane >> 4) << 3);
            const float* p = W_lin + n * 256 + k0;
            unsigned short h[8];
            #pragma unroll
            for (int j = 0; j < 8; ++j) h[j] = f2h(p[j]);
            uint4 v;
            v.x = (unsigned)h[0] | ((unsigned)h[1] << 16);
            v.y = (unsigned)h[2] | ((unsigned)h[3] << 16);
            v.z = (unsigned)h[4] | ((unsigned)h[5] << 16);
            v.w = (unsigned)h[6] | ((unsigned)h[7] << 16);
            wl[i2] = v;
        } else if (i < 41216) {
            int cb = i - 40960;
            bias0[cb] = make_float4(b_ih[cb] + b_hh[cb],
                                    b_ih[256 + cb] + b_hh[256 + cb],
                                    b_ih[512 + cb], b_hh[512 + cb]);
        }
        return;
    }
    int fb = blockIdx.x - 161;
    if (fb < 512) {                        // one wc tile per block, 4-way split
        const int tid  = threadIdx.x;
        const int q    = tid >> 6;         // ii quarter 0..3
        const int lane = tid & 63;
        const int tile = fb;
        int w = tile >> 5, r = tile & 31;
        int g = r >> 3, kt = r & 7;
        int c = (w << 4) + (lane & 15);
        int k0 = (kt << 5) + ((lane >> 4) << 3);
        float s[8];
        #pragma unroll
        for (int j = 0; j < 8; ++j) s[j] = 0.0f;
        if (g == 3) {
            if (q == 0) {
                #pragma unroll
                for (int j = 0; j < 8; ++j) s[j] = W_hh[(512 + c) * 256 + k0 + j];
            }
        } else {
            int row = g * 256 + c;
            const float* wi = W_ih + row * 128 + (q << 5);
            for (int ii = 0; ii < 32; ++ii) {
                float wv = wi[ii];
                const float* wrow = W_lin + ((q << 5) + ii) * 256 + k0;
                #pragma unroll
                for (int j = 0; j < 8; ++j) s[j] += wv * wrow[j];
            }
            if (g < 2 && q == 0) {
                #pragma unroll
                for (int j = 0; j < 8; ++j) s[j] += W_hh[row * 256 + k0 + j];
            }
        }
        #pragma unroll
        for (int j = 0; j < 8; ++j) sh[tid][j] = s[j];
        __syncthreads();
        if (q == 0) {
            #pragma unroll
            for (int j = 0; j < 8; ++j)
                s[j] += sh[tid + 64][j] + sh[tid + 128][j] + sh[tid + 192][j];
            unsigned short h[8];
            #pragma unroll
            for (int j = 0; j < 8; ++j) h[j] = f2h(s[j]);
            uint4 v;
            v.x = (unsigned)h[0] | ((unsigned)h[1] << 16);
            v.y = (unsigned)h[2] | ((unsigned)h[3] << 16);
            v.z = (unsigned)h[4] | ((unsigned)h[5] << 16);
            v.w = (unsigned)h[6] | ((unsigned)h[7] << 16);
            wc[tile * 64 + lane] = v;
        }
    } else {                               // fb == 512: folded biases
        int c = threadIdx.x;
        float d0 = 0.f, d1 = 0.f, d2 = 0.f;
        for (int ii = 0; ii < 128; ++ii) {
            float bl = b_lin[ii];
            d0 += bl * W_ih[c * 128 + ii];
            d1 += bl * W_ih[(256 + c) * 128 + ii];
            d2 += bl * W_ih[(512 + c) * 128 + ii];
        }
        bc[c] = make_float4(b_ih[c] + b_hh[c] + d0,
                            b_ih[256 + c] + b_hh[256 + c] + d1,
                            b_ih[512 + c] + d2,
                            b_hh[512 + c]);
    }
}

// ---------------------------------------------------------------------------
// Recurrence: 64 blocks x 1024 thr (16 waves, 4/SIMD). Block owns 16 batch
// rows; wave w (0..15) owns ONE col-group: cols c0 = w*16 .. w*16+15.
// Residency per wave (exactly fills the register pool at 4 waves/SIMD):
//   AGPR 16 tiles (64 AGPRs, "+a" pinned): r kt0-7, z kt0-7
//   LDS   8 tiles: in kt0-3 [slots 0-3], hn kt0-3 [slots 4-7]
//   streamed 8/step: in kt4-7 (tiles 20-23), hn kt4-7 (tiles 28-31),
//       all issued at loop top (32-VGPR peak)
// LDS (uint4): [0,1024) h-frag dbuf | [1024,1280) xbuf | [1280,9472)
// per-wave weight tiles (8/wave). One lgkm barrier/step. (R15/R16-verified)
// ---------------------------------------------------------------------------
__global__ __launch_bounds__(1024, 4) void gru_kernel(
    const float* __restrict__ inputs,
    const float* __restrict__ hidden,
    const uint4* __restrict__ wc,
    const uint4* __restrict__ w0,
    const float4* __restrict__ bias0,
    const float4* __restrict__ bcp,
    float* __restrict__ out)
{
    __shared__ uint4 lds[9472];            // 151552 B

    const int tid  = threadIdx.x;
    const int lane = tid & 63;
    const int w    = tid >> 6;             // wave 0..15
    const int quad = lane >> 4;
    const int nc   = lane & 15;
    const int r0   = blockIdx.x << 4;
    const int c0   = (w << 4) + nc;
    const float4 bc0 = bcp[c0];
    const uint4* wcw = wc + (size_t)w * 2048;         // 32 tiles * 64

    // ---- AGPR-pinned tiles: r kt0-7, z kt0-7 for this col-group
    half8 wr[8], wz[8];
    #pragma unroll
    for (int kt = 0; kt < 8; ++kt) {
        wr[kt] = ld_agpr(&wcw[kt * 64 + lane]);
        wz[kt] = ld_agpr(&wcw[(8 + kt) * 64 + lane]);
    }

    // ---- LDS-resident tiles: in kt0-3 (tiles 16-19), hn kt0-3 (tiles 24-27)
    const int wbase = 1280 + (w << 9);     // 512 uint4 per wave
    #pragma unroll
    for (int i = 0; i < 4; ++i) {
        lds[wbase + (i << 6) + lane]       = wcw[(16 + i) * 64 + lane];
        lds[wbase + ((4 + i) << 6) + lane] = wcw[(24 + i) * 64 + lane];
    }

    // fp32 master hidden state: rows quad*4+d, col c0
    float hreg[4];
    #pragma unroll
    for (int d = 0; d < 4; ++d)
        hreg[d] = hidden[(r0 + (quad << 2) + d) * 256 + c0];

    // A-frag write addressing: col c0 -> kt = w>>1, kp = (w&1)*16+nc;
    // frag lane lf = (kp>>3)*16 + quad*4; u16 idx = ((kt*64+lf)<<3)+(kp&7)
    unsigned short* lds_u16 = (unsigned short*)lds;
    const int kp  = ((w & 1) << 4) + nc;
    const int lf  = ((kp >> 3) << 4) + (quad << 2);
    const int hfb0 = (((w >> 1) * 64 + lf) << 3) + (kp & 7);

    // init h(0) frags -> buf0
    for (int idx = tid; idx < 2048; idx += 1024) {
        int ktl = idx >> 8;
        int rem = idx & 255;
        int lfr = rem >> 2, jg = rem & 3;
        int m = lfr & 15;
        int hc = ktl * 32 + (lfr >> 4) * 8 + jg * 2;
        const float* p = hidden + (r0 + m) * 256 + hc;
        unsigned pk = (unsigned)f2h(p[0]) | ((unsigned)f2h(p[1]) << 16);
        ((unsigned*)lds)[(ktl * 64 + lfr) * 4 + jg] = pk;
    }
    // init x frags -> xbuf
    {
        int idx = tid;
        int kt = idx >> 8, lfr = (idx >> 2) & 63, jg = idx & 3;
        int m = lfr & 15;
        int k0 = (kt << 5) + ((lfr >> 4) << 3) + (jg << 1);
        const float* p = inputs + (r0 + m) * 128 + k0;
        unsigned pk = (unsigned)f2h(p[0]) | ((unsigned)f2h(p[1]) << 16);
        ((unsigned*)lds)[(1024 + (kt << 6) + lfr) * 4 + jg] = pk;
    }
    __syncthreads();

    unsigned short* Hout = (unsigned short*)out;

    // ---- t = 0: K=384 on [x|h] with original w0 (streamed once)
    {
        const uint4* ww = w0 + (size_t)w * 2304;       // 36 tiles * 64
        floatx4 ar = {0.f,0.f,0.f,0.f}, az = {0.f,0.f,0.f,0.f};
        floatx4 ain = {0.f,0.f,0.f,0.f}, ahn = {0.f,0.f,0.f,0.f};
        #pragma unroll
        for (int kt = 0; kt < 12; ++kt) {
            half8 A = as_h8(kt < 4 ? lds[1024 + (kt << 6) + lane]
                                   : lds[((kt - 4) << 6) + lane]);
            ar = MFMA16(A, as_h8(ww[kt * 64 + lane]), ar);
            az = MFMA16(A, as_h8(ww[(12 + kt) * 64 + lane]), az);
            if (kt < 4)
                ain = MFMA16(A, as_h8(ww[(24 + kt) * 64 + lane]), ain);
            else
                ahn = MFMA16(A, as_h8(ww[(24 + kt) * 64 + lane]), ahn);
        }
        float4 b0 = bias0[c0];
        #pragma unroll
        for (int d = 0; d < 4; ++d) {
            float rr = sigm(ar[d] + b0.x);
            float zz = sigm(az[d] + b0.y);
            float nn = tanh_fast(ain[d] + b0.z + rr * (ahn[d] + b0.w));
            float hnew = (1.0f - zz) * nn + zz * hreg[d];
            hreg[d] = hnew;
            unsigned short hu = f2h(hnew);
            lds_u16[4096 + hfb0 + (d << 3)] = hu;      // buf1
            Hout[((size_t)(r0 + (quad << 2) + d) << 8) + c0] = hu;
        }
        bar_lgkm();
    }

    for (int t = 1; t < 256; ++t) {
        const int rb   = (t & 1) << 9;                 // read buf (uint4)
        const int wb16 = (((t + 1) & 1) << 9) << 3;    // write buf (u16)

        // opaque per-iteration pointer: streamed tiles cannot be hoisted
        const uint4* sp = wcw + lane;
        asm("" : "+v"(sp));

        // streamed tiles: in kt4-7 (tiles 20-23), hn kt4-7 (tiles 28-31).
        uint4 si[4], sh[4];
        si[0] = sp[20 * 64]; si[1] = sp[21 * 64];
        si[2] = sp[22 * 64]; si[3] = sp[23 * 64];
        sh[0] = sp[28 * 64]; sh[1] = sp[29 * 64];
        sh[2] = sp[30 * 64]; sh[3] = sp[31 * 64];

        floatx4 ar = {0.f,0.f,0.f,0.f}, az = {0.f,0.f,0.f,0.f};
        floatx4 ai = {0.f,0.f,0.f,0.f}, ah = {0.f,0.f,0.f,0.f};

        #pragma unroll
        for (int kt = 0; kt < 8; ++kt) {
            half8 A = as_h8(lds[rb + (kt << 6) + lane]);
            ar = MFMA16(A, wr[kt], ar);
            az = MFMA16(A, wz[kt], az);
            half8 Bi = (kt < 4) ? as_h8(lds[wbase + (kt << 6) + lane])
                                : as_h8(si[kt - 4]);
            ai = MFMA16(A, Bi, ai);
            half8 Bh = (kt < 4) ? as_h8(lds[wbase + ((4 + kt) << 6) + lane])
                                : as_h8(sh[kt - 4]);
            ah = MFMA16(A, Bh, ah);
        }

        const size_t obase = (size_t)t * 1024 + r0 + (quad << 2);
        #pragma unroll
        for (int d = 0; d < 4; ++d) {
            float rr = sigm(ar[d] + bc0.x);
            float zz = sigm(az[d] + bc0.y);
            float nn = tanh_fast(ai[d] + bc0.z + rr * (ah[d] + bc0.w));
            float hnew = (1.0f - zz) * nn + zz * hreg[d];
            hreg[d] = hnew;
            unsigned short hu = f2h(hnew);
            lds_u16[wb16 + hfb0 + (d << 3)] = hu;
            Hout[((obase + d) << 8) + c0] = hu;
        }
        bar_lgkm();
    }
}

// ---------------------------------------------------------------------------
// yfused: one block per timestep t (grid 256, 1/CU, 512 thr = 8 waves).
// Phase 1: wave w computes y rows [w*128, w*128+128) x all 128 cols:
//   A-frags straight from H global (u16), B from 64KB LDS (all W_lin tiles),
//   y packed fp16 -> 32 uintx4/thread pinned in AGPRs; s1/s2 fp32 per lane.
// Phase 2: shfl + LDS reduce -> mean/scale per channel.
// Phase 3: unpack AGPR y, normalize, write fp32 out. In-place over d_out:
//   all H reads are consumed by phase-1 MFMAs before the stats barrier.
// (R11/R16-verified; R17's 16-wave variant was neutral-to-negative ->
// yfused is L3-BW-bound, 8 waves suffice.)
// ---------------------------------------------------------------------------
__global__ __launch_bounds__(512, 2) void yfused_kernel(
    const uint4* __restrict__ wl, const float* __restrict__ b_lin,
    float* __restrict__ out)
{
    __shared__ uint4 bfr[4096];            // 64 KB: 64 W_lin tiles
    __shared__ float sred[8][256];         // 8 KB: per-wave s1[128] | s2[128]
    __shared__ float snorm[256];           // mean[128] | scale[128]

    const int tid  = threadIdx.x;
    const int lane = tid & 63;
    const int w    = tid >> 6;
    const int quad = lane >> 4;
    const int nc   = lane & 15;
    const int t    = blockIdx.x;

    const unsigned short* H = (const unsigned short*)out + (size_t)t * 262144;
    float* Y = out + (size_t)t * 131072;

    // stage all W_lin B-frags
    #pragma unroll
    for (int i = 0; i < 8; ++i)
        bfr[(i << 9) + tid] = wl[(i << 9) + tid];

    float blv[8];
    #pragma unroll
    for (int c = 0; c < 8; ++c) blv[c] = b_lin[(c << 4) + nc];

    __syncthreads();

    const int rw0 = w << 7;                // wave's first row of 128
    float s1[8], s2[8];
    #pragma unroll
    for (int c = 0; c < 8; ++c) { s1[c] = 0.f; s2[c] = 0.f; }
    uintx4 ypk[32];

    #pragma unroll
    for (int s = 0; s < 8; ++s) {
        const unsigned short* hrow = H + (size_t)(rw0 + (s << 4) + nc) * 256 + (quad << 3);
        uint4 A[8];
        #pragma unroll
        for (int kt = 0; kt < 8; ++kt)
            A[kt] = *(const uint4*)(hrow + (kt << 5));
        unsigned te0 = 0, te1 = 0;
        #pragma unroll
        for (int c = 0; c < 8; ++c) {
            floatx4 acc = {0.f, 0.f, 0.f, 0.f};
            #pragma unroll
            for (int kt = 0; kt < 8; ++kt)
                acc = MFMA16(as_h8(A[kt]), as_h8(bfr[(((c << 3) + kt) << 6) + lane]), acc);
            float y0 = acc[0] + blv[c], y1 = acc[1] + blv[c];
            float y2 = acc[2] + blv[c], y3 = acc[3] + blv[c];
            s1[c] += (y0 + y1) + (y2 + y3);
            s2[c] += (y0 * y0 + y1 * y1) + (y2 * y2 + y3 * y3);
            unsigned q0 = pack2h(y0, y1), q1 = pack2h(y2, y3);
            if ((c & 1) == 0) { te0 = q0; te1 = q1; }
            else {
                uintx4 v; v[0] = te0; v[1] = te1; v[2] = q0; v[3] = q1;
                asm volatile("; ypin" : "+a"(v));
                ypk[(s << 2) + (c >> 1)] = v;
            }
        }
    }

    // cross-quad then cross-wave stats reduce
    #pragma unroll
    for (int c = 0; c < 8; ++c) {
        s1[c] += __shfl_xor(s1[c], 16); s1[c] += __shfl_xor(s1[c], 32);
        s2[c] += __shfl_xor(s2[c], 16); s2[c] += __shfl_xor(s2[c], 32);
    }
    if (lane < 16) {
        #pragma unroll
        for (int c = 0; c < 8; ++c) {
            sred[w][(c << 4) + lane]       = s1[c];
            sred[w][128 + (c << 4) + lane] = s2[c];
        }
    }
    __syncthreads();
    if (tid < 128) {
        float a1 = 0.f, a2 = 0.f;
        #pragma unroll
        for (int w2 = 0; w2 < 8; ++w2) {
            a1 += sred[w2][tid];
            a2 += sred[w2][128 + tid];
        }
        float mean = a1 * (1.0f / 1024.0f);
        float var  = a2 * (1.0f / 1024.0f) - mean * mean;
        snorm[tid]       = mean;
        snorm[128 + tid] = rsqrtf(var + EPS_BN);
    }
    __syncthreads();

    float mn[8], scl[8];
    #pragma unroll
    for (int c = 0; c < 8; ++c) {
        mn[c]  = snorm[(c << 4) + nc];
        scl[c] = snorm[128 + (c << 4) + nc];
    }

    #pragma unroll
    for (int s = 0; s < 8; ++s) {
        float* yrow = Y + (size_t)(rw0 + (s << 4) + (quad << 2)) * 128 + nc;
        #pragma unroll
        for (int cp = 0; cp < 4; ++cp) {
            uintx4 v = ypk[(s << 2) + cp];
            const int c0 = cp << 1, c1 = c0 + 1;
            float2 a01 = up2(v[0]), a23 = up2(v[1]);   // col-tile c0, d0..3
            float2 b01 = up2(v[2]), b23 = up2(v[3]);   // col-tile c1, d0..3
            const int o0 = cp << 5, o1 = o0 + 16;
            yrow[0 * 128 + o0] = (a01.x - mn[c0]) * scl[c0];
            yrow[1 * 128 + o0] = (a01.y - mn[c0]) * scl[c0];
            yrow[2 * 128 + o0] = (a23.x - mn[c0]) * scl[c0];
            yrow[3 * 128 + o0] = (a23.y - mn[c0]) * scl[c0];
            yrow[0 * 128 + o1] = (b01.x - mn[c1]) * scl[c1];
            yrow[1 * 128 + o1] = (b01.y - mn[c1]) * scl[c1];
            yrow[2 * 128 + o1] = (b23.x - mn[c1]) * scl[c1];
            yrow[3 * 128 + o1] = (b23.y - mn[c1]) * scl[c1];
        }
    }
}

extern "C" void kernel_launch(void* const* d_in, const int* in_sizes, int n_in,
                              void* d_out, int out_size, void* d_ws, size_t ws_size,
                              hipStream_t stream) {
    (void)in_sizes; (void)n_in; (void)out_size; (void)ws_size;
    const float* inputs = (const float*)d_in[0];
    const float* hidden = (const float*)d_in[1];
    const float* W_ih   = (const float*)d_in[2];
    const float* b_ih   = (const float*)d_in[3];
    const float* W_hh   = (const float*)d_in[4];
    const float* b_hh   = (const float*)d_in[5];
    const float* W_lin  = (const float*)d_in[6];
    const float* b_lin  = (const float*)d_in[7];

    char* ws = (char*)d_ws;
    uint4*  wcp   = (uint4*)(ws + WS_WC);
    uint4*  w0p   = (uint4*)(ws + WS_W0);
    uint4*  wlp   = (uint4*)(ws + WS_WL);
    float4* bias0 = (float4*)(ws + WS_B0);
    float4* bcp   = (float4*)(ws + WS_BC);

    pack_all_kernel<<<674, 256, 0, stream>>>(W_ih, W_hh, W_lin, b_ih, b_hh, b_lin,
                                             w0p, wlp, bias0, wcp, bcp);
    gru_kernel<<<64, 1024, 0, stream>>>(inputs, hidden, wcp, w0p, bias0, bcp, (float*)d_out);
    yfused_kernel<<<256, 512, 0, stream>>>(wlp, b_lin, (float*)d_out);
}